// Round 9
// baseline (116.411 us; speedup 1.0000x reference)
//
#include <hip/hip_runtime.h>

// SSIM3D on (8,1,32,256,256) f32, separable Gaussian (5,11,11).
// fp16-packed pipeline, 32 VGPR / 8 blocks/CU. R9 change: PDW 22->23 (odd LDS
// row stride) to break the stride-22 bank-conflict patterns (1.15e7 conflicts
// in R8). LDS/block 20256B -> rounds to 20480 -> still exactly 8 blocks/CU.

typedef __attribute__((ext_vector_type(2))) float f32x2;
typedef _Float16 h2 __attribute__((ext_vector_type(2)));

#define DEPTH   32
#define HEIGHT  256
#define WIDTH   256
#define HW      (HEIGHT*WIDTH)
#define COUNT   16777216.0
#define NACC    64

#define PDW   23            // h2 slots per row (44 used + 1 pad), ODD stride
#define PLSZ  (44*PDW)      // 1012 h2 per plane (rows 0..41 halo, 42..43 scratch)

// fp16 bit patterns: wy (sigma=1.5, n=11) and wz (sigma=0.7, n=5), normalized
#define W0h 0x1436u  // 0.00102852
#define W1h 0x1FC8u  // 0.00759876
#define W2h 0x289Cu  // 0.03600077
#define W3h 0x2F00u  // 0.10936070
#define W4h 0x32D1u  // 0.21300540
#define W5h 0x3442u  // 0.26601330

__device__ __forceinline__ h2 h2bits(unsigned u) {
  h2 r; __builtin_memcpy(&r, &u, 4); return r;
}
__device__ __forceinline__ h2 hfma2v(h2 a, h2 b, h2 c) {
  return __builtin_elementwise_fma(a, b, c);
}
__device__ __forceinline__ h2 pkrtz(float x, float y) {
#if __has_builtin(__builtin_amdgcn_cvt_pkrtz)
  auto t = __builtin_amdgcn_cvt_pkrtz(x, y);   // __fp16 ext_vector(2)
  h2 r; __builtin_memcpy(&r, &t, 4); return r;
#else
  h2 r; r.x = (_Float16)x; r.y = (_Float16)y; return r;
#endif
}

__global__ __launch_bounds__(256, 6) void ssim3d_h16d(
    const float* __restrict__ img1, const float* __restrict__ img2,
    double* __restrict__ acc)
{
  __shared__ __align__(16) h2 PL[5 * PLSZ];   // 20,240 B
  __shared__ float wred[4];
  const int tid = threadIdx.x;

  // broadcast fp16 weight constants (folded to SGPR/imm at compile time)
  constexpr unsigned WYB[11] = {
    W0h|(W0h<<16), W1h|(W1h<<16), W2h|(W2h<<16), W3h|(W3h<<16), W4h|(W4h<<16),
    W5h|(W5h<<16),
    W4h|(W4h<<16), W3h|(W3h<<16), W2h|(W2h<<16), W1h|(W1h<<16), W0h|(W0h<<16)};
  constexpr unsigned WZB[5] = {
    0x20ED20EDu, 0x32933293u, 0x388F388Fu, 0x32933293u, 0x20ED20EDu};
  // x-conv weight pairs WP[k][m]: lo16 = wy[2m-k-1], hi16 = wy[2m-k] (OOR -> 0)
  constexpr unsigned WP[4][8] = {
    {0x14360000u, 0x289C1FC8u, 0x32D12F00u, 0x32D13442u, 0x289C2F00u, 0x14361FC8u, 0u, 0u},
    {0u, 0x1FC81436u, 0x2F00289Cu, 0x344232D1u, 0x2F0032D1u, 0x1FC8289Cu, 0x00001436u, 0u},
    {0u, 0x14360000u, 0x289C1FC8u, 0x32D12F00u, 0x32D13442u, 0x289C2F00u, 0x14361FC8u, 0u},
    {0u, 0u, 0x1FC81436u, 0x2F00289Cu, 0x344232D1u, 0x2F0032D1u, 0x1FC8289Cu, 0x00001436u}};

  // ---- block decode + XCD swizzle (one batch n per XCD)
  int bid = blockIdx.x;
  bid = (bid & 7) * 2048 + (bid >> 3);
  const int txi = bid & 7, tyi = (bid >> 3) & 7, z_out = (bid >> 6) & 31, n = bid >> 11;
  const int x0 = txi * 32 - 6;   // even halo origin (44 cols)
  const int y0 = tyi * 32 - 5;   // halo rows 0..41 used

  // ---- stage 1: z-conv of 5 fields, packed fp16 accumulation
  const int cp = tid % 22, g = tid / 22;   // cols {2cp,2cp+1}, rows 4g..4g+3
  h2 zacc[4][5];
#pragma unroll
  for (int i = 0; i < 4; ++i)
#pragma unroll
    for (int f = 0; f < 5; ++f) zacc[i][f] = (h2){(_Float16)0, (_Float16)0};

  if (g < 11) {
    const int gx0 = x0 + 2 * cp;
    if ((unsigned)gx0 <= 254u) {   // pair fully in-bounds (else stays zero)
      const size_t nbase = (size_t)n * DEPTH * HW;
      int rofs[4];
#pragma unroll
      for (int i = 0; i < 4; ++i) {
        int gy = y0 + 4 * g + i;                 // OOB rows: clamped data,
        rofs[i] = min(max(gy, 0), 255) * WIDTH;  // zeroed at stage-3 read
      }
#pragma unroll
      for (int kz = 0; kz < 5; ++kz) {
        int z_in = z_out + kz - 2;
        if ((unsigned)z_in >= 32u) continue;     // zero pad in z (uniform)
        const h2 wzh = h2bits(WZB[kz]);
        const float* p1 = img1 + nbase + (size_t)z_in * HW + gx0;
        const float* p2 = img2 + nbase + (size_t)z_in * HW + gx0;
#pragma unroll
        for (int i = 0; i < 4; ++i) {
          f32x2 A = *(const f32x2*)(p1 + rofs[i]);
          f32x2 B = *(const f32x2*)(p2 + rofs[i]);
          h2 ah = pkrtz(A.x, A.y), bh = pkrtz(B.x, B.y);
          zacc[i][0] = hfma2v(wzh, ah, zacc[i][0]);
          zacc[i][1] = hfma2v(wzh, bh, zacc[i][1]);
          zacc[i][2] = hfma2v(wzh, ah * ah, zacc[i][2]);
          zacc[i][3] = hfma2v(wzh, bh * bh, zacc[i][3]);
          zacc[i][4] = hfma2v(wzh, ah * bh, zacc[i][4]);
        }
      }
    }
    // ---- stage 2: b32 stores (already fp16)
#pragma unroll
    for (int i = 0; i < 4; ++i) {
      int row = 4 * g + i;
#pragma unroll
      for (int f = 0; f < 5; ++f)
        PL[f * PLSZ + row * PDW + cp] = zacc[i][f];
    }
  }
  __syncthreads();   // planes ready

  // ---- stage 3: per-field in-place y-conv (packed fp16)
  const int g2 = tid / 22, xp = tid % 22;   // rows 3g2..3g2+2, col-pair xp
  const bool act3 = (g2 < 11);
  const bool yedge = (tyi == 0) || (tyi == 7);
#pragma unroll
  for (int f = 0; f < 5; ++f) {
    h2 yout[3];
    if (act3) {
      const h2* pf = PL + f * PLSZ + xp;
      h2 win[13];
#pragma unroll
      for (int i = 0; i < 13; ++i) win[i] = pf[(3 * g2 + i) * PDW];
      if (yedge) {   // block-uniform: zero OOB halo rows
#pragma unroll
        for (int i = 0; i < 13; ++i)
          if ((unsigned)(y0 + 3 * g2 + i) >= 256u)
            win[i] = (h2){(_Float16)0, (_Float16)0};
      }
#pragma unroll
      for (int r = 0; r < 3; ++r) {
        h2 s = (h2){(_Float16)0, (_Float16)0};
#pragma unroll
        for (int j = 0; j < 11; ++j) s = hfma2v(h2bits(WYB[j]), win[r + j], s);
        yout[r] = s;
      }
    }
    __syncthreads();   // all reads of plane f done
    if (act3) {
#pragma unroll
      for (int r = 0; r < 3; ++r) {
        int y = 3 * g2 + r;
        if (y < 32) PL[f * PLSZ + y * PDW + xp] = yout[r];
      }
    }
  }
  __syncthreads();   // all y-writes visible

  // ---- stage 4: packed fp16 x-conv + f32 SSIM; row = tid&31, cols 4xh..4xh+3
  const int yy = tid & 31;
  const int xh = tid >> 5;
  float sf[5][4];
#pragma unroll
  for (int f = 0; f < 5; ++f) {
    const h2* pp = PL + f * PLSZ + yy * PDW + xh * 2;
    h2 d[8];
#pragma unroll
    for (int m = 0; m < 8; ++m) d[m] = pp[m];
#pragma unroll
    for (int k = 0; k < 4; ++k) {
      h2 a = (h2){(_Float16)0, (_Float16)0};
#pragma unroll
      for (int m = 0; m < 8; ++m)
        if (WP[k][m]) a = hfma2v(h2bits(WP[k][m]), d[m], a);
      sf[f][k] = (float)a.x + (float)a.y;
    }
  }

  float lsum = 0.f;
  const float C1 = 1e-4f, C2 = 9e-4f;
#pragma unroll
  for (int k = 0; k < 4; ++k) {
    float mu1 = sf[0][k], mu2 = sf[1][k];
    float m11 = mu1 * mu1, m22 = mu2 * mu2, m12 = mu1 * mu2;
    float s1 = sf[2][k] - m11, s2 = sf[3][k] - m22, s12 = sf[4][k] - m12;
    float num = fmaf(2.f, m12, C1) * fmaf(2.f, s12, C2);
    float den = (m11 + m22 + C1) * (s1 + s2 + C2);
#if __has_builtin(__builtin_amdgcn_rcpf)
    lsum = fmaf(num, __builtin_amdgcn_rcpf(den), lsum);
#else
    lsum += num / den;
#endif
  }

  // ---- reduction
#pragma unroll
  for (int off = 32; off > 0; off >>= 1) lsum += __shfl_down(lsum, off, 64);
  if ((tid & 63) == 0) wred[tid >> 6] = lsum;
  __syncthreads();
  if (tid == 0) {
    float bs = wred[0] + wred[1] + wred[2] + wred[3];
    atomicAdd(&acc[blockIdx.x & (NACC - 1)], (double)bs);
  }
}

__global__ void ssim3d_finalize(const double* __restrict__ acc, float* __restrict__ out)
{
  double s = 0.0;
  for (int i = 0; i < NACC; ++i) s += acc[i];
  out[0] = 1.0f - (float)(s / COUNT);
}

extern "C" void kernel_launch(void* const* d_in, const int* in_sizes, int n_in,
                              void* d_out, int out_size, void* d_ws, size_t ws_size,
                              hipStream_t stream)
{
  const float* img1 = (const float*)d_in[0];
  const float* img2 = (const float*)d_in[1];
  float* out = (float*)d_out;
  double* acc = (double*)d_ws;

  (void)hipMemsetAsync(d_ws, 0, NACC * sizeof(double), stream);

  const int n_blocks = 8 * DEPTH * 8 * 8;   // 16384
  ssim3d_h16d<<<dim3(n_blocks), dim3(256), 0, stream>>>(img1, img2, acc);
  ssim3d_finalize<<<1, 1, 0, stream>>>(acc, out);
}

// Round 10
// 108.308 us; speedup vs baseline: 1.0748x; 1.0748x over previous
//
#include <hip/hip_runtime.h>

// SSIM3D on (8,1,32,256,256) f32, separable Gaussian (5,11,11).
// fp16-packed pipeline, 32 VGPR / 8 blocks/CU (32-waves/CU cap).
// R10: algebraic 5->4 field reduction — SSIM only needs sigma1^2+sigma2^2,
// so convolve (a^2+b^2) as ONE field. Fields: a, b, a^2+b^2, a*b.

typedef __attribute__((ext_vector_type(2))) float f32x2;
typedef _Float16 h2 __attribute__((ext_vector_type(2)));

#define DEPTH   32
#define HEIGHT  256
#define WIDTH   256
#define HW      (HEIGHT*WIDTH)
#define COUNT   16777216.0
#define NACC    64
#define NF      4           // fields: a, b, a^2+b^2, a*b

#define PDW   23            // h2 slots per row (44 used + 1 pad)
#define PLSZ  (44*PDW)      // 1012 h2 per plane (rows 0..41 halo, 42..43 scratch)

// fp16 bit patterns: wy (sigma=1.5, n=11) and wz (sigma=0.7, n=5), normalized
#define W0h 0x1436u  // 0.00102852
#define W1h 0x1FC8u  // 0.00759876
#define W2h 0x289Cu  // 0.03600077
#define W3h 0x2F00u  // 0.10936070
#define W4h 0x32D1u  // 0.21300540
#define W5h 0x3442u  // 0.26601330

__device__ __forceinline__ h2 h2bits(unsigned u) {
  h2 r; __builtin_memcpy(&r, &u, 4); return r;
}
__device__ __forceinline__ h2 hfma2v(h2 a, h2 b, h2 c) {
  return __builtin_elementwise_fma(a, b, c);
}
__device__ __forceinline__ h2 pkrtz(float x, float y) {
#if __has_builtin(__builtin_amdgcn_cvt_pkrtz)
  auto t = __builtin_amdgcn_cvt_pkrtz(x, y);   // __fp16 ext_vector(2)
  h2 r; __builtin_memcpy(&r, &t, 4); return r;
#else
  h2 r; r.x = (_Float16)x; r.y = (_Float16)y; return r;
#endif
}

__global__ __launch_bounds__(256, 6) void ssim3d_h16e(
    const float* __restrict__ img1, const float* __restrict__ img2,
    double* __restrict__ acc)
{
  __shared__ __align__(16) h2 PL[NF * PLSZ];   // 16,192 B
  __shared__ float wred[4];
  const int tid = threadIdx.x;

  // broadcast fp16 weight constants (folded to SGPR/imm at compile time)
  constexpr unsigned WYB[11] = {
    W0h|(W0h<<16), W1h|(W1h<<16), W2h|(W2h<<16), W3h|(W3h<<16), W4h|(W4h<<16),
    W5h|(W5h<<16),
    W4h|(W4h<<16), W3h|(W3h<<16), W2h|(W2h<<16), W1h|(W1h<<16), W0h|(W0h<<16)};
  constexpr unsigned WZB[5] = {
    0x20ED20EDu, 0x32933293u, 0x388F388Fu, 0x32933293u, 0x20ED20EDu};
  // x-conv weight pairs WP[k][m]: lo16 = wy[2m-k-1], hi16 = wy[2m-k] (OOR -> 0)
  constexpr unsigned WP[4][8] = {
    {0x14360000u, 0x289C1FC8u, 0x32D12F00u, 0x32D13442u, 0x289C2F00u, 0x14361FC8u, 0u, 0u},
    {0u, 0x1FC81436u, 0x2F00289Cu, 0x344232D1u, 0x2F0032D1u, 0x1FC8289Cu, 0x00001436u, 0u},
    {0u, 0x14360000u, 0x289C1FC8u, 0x32D12F00u, 0x32D13442u, 0x289C2F00u, 0x14361FC8u, 0u},
    {0u, 0u, 0x1FC81436u, 0x2F00289Cu, 0x344232D1u, 0x2F0032D1u, 0x1FC8289Cu, 0x00001436u}};

  // ---- block decode + XCD swizzle (one batch n per XCD)
  int bid = blockIdx.x;
  bid = (bid & 7) * 2048 + (bid >> 3);
  const int txi = bid & 7, tyi = (bid >> 3) & 7, z_out = (bid >> 6) & 31, n = bid >> 11;
  const int x0 = txi * 32 - 6;   // even halo origin (44 cols)
  const int y0 = tyi * 32 - 5;   // halo rows 0..41 used

  // ---- stage 1: z-conv of 4 fields, packed fp16 accumulation
  const int cp = tid % 22, g = tid / 22;   // cols {2cp,2cp+1}, rows 4g..4g+3
  h2 zacc[4][NF];
#pragma unroll
  for (int i = 0; i < 4; ++i)
#pragma unroll
    for (int f = 0; f < NF; ++f) zacc[i][f] = (h2){(_Float16)0, (_Float16)0};

  if (g < 11) {
    const int gx0 = x0 + 2 * cp;
    if ((unsigned)gx0 <= 254u) {   // pair fully in-bounds (else stays zero)
      const size_t nbase = (size_t)n * DEPTH * HW;
      int rofs[4];
#pragma unroll
      for (int i = 0; i < 4; ++i) {
        int gy = y0 + 4 * g + i;                 // OOB rows: clamped data,
        rofs[i] = min(max(gy, 0), 255) * WIDTH;  // zeroed at stage-3 read
      }
#pragma unroll
      for (int kz = 0; kz < 5; ++kz) {
        int z_in = z_out + kz - 2;
        if ((unsigned)z_in >= 32u) continue;     // zero pad in z (uniform)
        const h2 wzh = h2bits(WZB[kz]);
        const float* p1 = img1 + nbase + (size_t)z_in * HW + gx0;
        const float* p2 = img2 + nbase + (size_t)z_in * HW + gx0;
#pragma unroll
        for (int i = 0; i < 4; ++i) {
          f32x2 A = *(const f32x2*)(p1 + rofs[i]);
          f32x2 B = *(const f32x2*)(p2 + rofs[i]);
          h2 ah = pkrtz(A.x, A.y), bh = pkrtz(B.x, B.y);
          h2 ss = hfma2v(ah, ah, bh * bh);       // a^2 + b^2
          zacc[i][0] = hfma2v(wzh, ah, zacc[i][0]);
          zacc[i][1] = hfma2v(wzh, bh, zacc[i][1]);
          zacc[i][2] = hfma2v(wzh, ss, zacc[i][2]);
          zacc[i][3] = hfma2v(wzh, ah * bh, zacc[i][3]);
        }
      }
    }
    // ---- stage 2: b32 stores (already fp16)
#pragma unroll
    for (int i = 0; i < 4; ++i) {
      int row = 4 * g + i;
#pragma unroll
      for (int f = 0; f < NF; ++f)
        PL[f * PLSZ + row * PDW + cp] = zacc[i][f];
    }
  }
  __syncthreads();   // planes ready

  // ---- stage 3: per-field in-place y-conv (packed fp16)
  const int g2 = tid / 22, xp = tid % 22;   // rows 3g2..3g2+2, col-pair xp
  const bool act3 = (g2 < 11);
  const bool yedge = (tyi == 0) || (tyi == 7);
#pragma unroll
  for (int f = 0; f < NF; ++f) {
    h2 yout[3];
    if (act3) {
      const h2* pf = PL + f * PLSZ + xp;
      h2 win[13];
#pragma unroll
      for (int i = 0; i < 13; ++i) win[i] = pf[(3 * g2 + i) * PDW];
      if (yedge) {   // block-uniform: zero OOB halo rows
#pragma unroll
        for (int i = 0; i < 13; ++i)
          if ((unsigned)(y0 + 3 * g2 + i) >= 256u)
            win[i] = (h2){(_Float16)0, (_Float16)0};
      }
#pragma unroll
      for (int r = 0; r < 3; ++r) {
        h2 s = (h2){(_Float16)0, (_Float16)0};
#pragma unroll
        for (int j = 0; j < 11; ++j) s = hfma2v(h2bits(WYB[j]), win[r + j], s);
        yout[r] = s;
      }
    }
    __syncthreads();   // all reads of plane f done
    if (act3) {
#pragma unroll
      for (int r = 0; r < 3; ++r) {
        int y = 3 * g2 + r;
        if (y < 32) PL[f * PLSZ + y * PDW + xp] = yout[r];
      }
    }
  }
  __syncthreads();   // all y-writes visible

  // ---- stage 4: packed fp16 x-conv + f32 SSIM; row = tid&31, cols 4xh..4xh+3
  const int yy = tid & 31;
  const int xh = tid >> 5;
  float sf[NF][4];
#pragma unroll
  for (int f = 0; f < NF; ++f) {
    const h2* pp = PL + f * PLSZ + yy * PDW + xh * 2;
    h2 d[8];
#pragma unroll
    for (int m = 0; m < 8; ++m) d[m] = pp[m];
#pragma unroll
    for (int k = 0; k < 4; ++k) {
      h2 a = (h2){(_Float16)0, (_Float16)0};
#pragma unroll
      for (int m = 0; m < 8; ++m)
        if (WP[k][m]) a = hfma2v(h2bits(WP[k][m]), d[m], a);
      sf[f][k] = (float)a.x + (float)a.y;
    }
  }

  float lsum = 0.f;
  const float C1 = 1e-4f, C2 = 9e-4f;
#pragma unroll
  for (int k = 0; k < 4; ++k) {
    float mu1 = sf[0][k], mu2 = sf[1][k];
    float mps = fmaf(mu1, mu1, mu2 * mu2);   // mu1^2 + mu2^2
    float m12 = mu1 * mu2;
    float s12 = sf[3][k] - m12;              // sigma12
    float sps = sf[2][k] - mps;              // sigma1^2 + sigma2^2
    float num = fmaf(2.f, m12, C1) * fmaf(2.f, s12, C2);
    float den = (mps + C1) * (sps + C2);
#if __has_builtin(__builtin_amdgcn_rcpf)
    lsum = fmaf(num, __builtin_amdgcn_rcpf(den), lsum);
#else
    lsum += num / den;
#endif
  }

  // ---- reduction
#pragma unroll
  for (int off = 32; off > 0; off >>= 1) lsum += __shfl_down(lsum, off, 64);
  if ((tid & 63) == 0) wred[tid >> 6] = lsum;
  __syncthreads();
  if (tid == 0) {
    float bs = wred[0] + wred[1] + wred[2] + wred[3];
    atomicAdd(&acc[blockIdx.x & (NACC - 1)], (double)bs);
  }
}

__global__ void ssim3d_finalize(const double* __restrict__ acc, float* __restrict__ out)
{
  double s = 0.0;
  for (int i = 0; i < NACC; ++i) s += acc[i];
  out[0] = 1.0f - (float)(s / COUNT);
}

extern "C" void kernel_launch(void* const* d_in, const int* in_sizes, int n_in,
                              void* d_out, int out_size, void* d_ws, size_t ws_size,
                              hipStream_t stream)
{
  const float* img1 = (const float*)d_in[0];
  const float* img2 = (const float*)d_in[1];
  float* out = (float*)d_out;
  double* acc = (double*)d_ws;

  (void)hipMemsetAsync(d_ws, 0, NACC * sizeof(double), stream);

  const int n_blocks = 8 * DEPTH * 8 * 8;   // 16384
  ssim3d_h16e<<<dim3(n_blocks), dim3(256), 0, stream>>>(img1, img2, acc);
  ssim3d_finalize<<<1, 1, 0, stream>>>(acc, out);
}